// Round 12
// baseline (12038.438 us; speedup 1.0000x reference)
//
#include <hip/hip_runtime.h>
#include <stdint.h>

typedef _Float16 f16;
typedef _Float16 f16x8 __attribute__((ext_vector_type(8)));
typedef float f32x4 __attribute__((ext_vector_type(4)));

#define MFMA16(a, b, c) __builtin_amdgcn_mfma_f32_16x16x32_f16((a), (b), (c), 0, 0, 0)

// Sizes: B=64, S=512, I=512, H=1024, 4H=4096, O=64

// ---------------- prep kernels ----------------

__global__ void k_conv_x(const float* __restrict__ x, f16* __restrict__ x16) {
  int i = blockIdx.x * 256 + threadIdx.x;
  int o = i * 8;
  int s = o >> 15, b = (o >> 9) & 63, c = o & 511;
  const float* src = x + (size_t)b * 262144 + (size_t)s * 512 + c;
  float4 v0 = *(const float4*)(src);
  float4 v1 = *(const float4*)(src + 4);
  union { f16 h[8]; f16x8 v; } t;
  t.h[0] = (f16)v0.x; t.h[1] = (f16)v0.y; t.h[2] = (f16)v0.z; t.h[3] = (f16)v0.w;
  t.h[4] = (f16)v1.x; t.h[5] = (f16)v1.y; t.h[6] = (f16)v1.z; t.h[7] = (f16)v1.w;
  *(f16x8*)(x16 + o) = t.v;
}

// Weights -> per-(colgroup,wave,kk,cf) MFMA B-fragments, f32->f16.
// fid = ((jc*8 + w)*KK + kk)*4 + cf. Lane holds W[c][k..k+7]:
//   slab col c = cf*16 + (lane&15) -> gate row g = (c>>4)*1024 + jc*16 + (c&15)
// K mapping (dependency-split per wave):
//   mode0 (L0, KK=6): kk<2 -> k = w*64  + kk*32      (x part, 0..511)
//                     kk>=2 -> k = 512 + w*128 + (kk-2)*32  (h0 part)
//   mode1 (L1, KK=8): kk<4 -> k = w*128 + kk*32      (h0 part, 0..1023)
//                     kk>=4 -> k = 1024 + w*128 + (kk-4)*32 (h1 part)
__global__ void k_conv_wfrag(const float* __restrict__ Wih, const float* __restrict__ Whh,
                             f16* __restrict__ Wf, int KI, int KK, int mode) {
  int fid = blockIdx.x;
  int lane = threadIdx.x;
  int cf = fid & 3; int rest = fid >> 2;
  int kk = rest % KK; rest /= KK; int w = rest & 7; int jc = rest >> 3;
  int c = cf * 16 + (lane & 15);
  int g = (c >> 4) * 1024 + jc * 16 + (c & 15);
  int k;
  if (mode == 0) k = (kk < 2) ? (w * 64 + kk * 32) : (512 + w * 128 + (kk - 2) * 32);
  else           k = (kk < 4) ? (w * 128 + kk * 32) : (1024 + w * 128 + (kk - 4) * 32);
  k += (lane >> 4) << 3;
  const float* src = (k < KI) ? (Wih + (size_t)g * KI + k)
                              : (Whh + (size_t)g * 1024 + (k - KI));
  union { f16 h[8]; f16x8 v; } t;
#pragma unroll
  for (int i = 0; i < 8; ++i) t.h[i] = (f16)src[i];
  *(f16x8*)(Wf + ((size_t)fid * 64 + lane) * 8) = t.v;
}

__global__ void k_conv_bias(const float* __restrict__ bih, const float* __restrict__ bhh,
                            float* __restrict__ br) {
  int d = blockIdx.x * 64 + threadIdx.x;  // 4096: d = jc*64 + c
  int jc = d >> 6, c = d & 63;
  int g = (c >> 4) * 1024 + jc * 16 + (c & 15);
  br[d] = bih[g] + bhh[g];
}

__global__ void k_conv_wfc(const float* __restrict__ Wfc, f16* __restrict__ Wfc16) {
  int i = blockIdx.x * 256 + threadIdx.x;
  Wfc16[i] = (f16)Wfc[i];
}

// ---------------- persistent pipelined LSTM ----------------
// 256 blocks x 512 threads, cooperative, 1 block/CU. layer = bid>>7;
// sub = bid&127; rh = sub>>6 (32-row half), jc = sub&63 (16 h-cols).
// Dependency-split scheduling:
//  - per-WAVE polling (dwordx2/lane over the 512B same-rh flag set; no barrier)
//  - per-wave K-slices split by operand (x / h0 / h1) so loads issue the
//    moment their own flag set clears; L0's WAR poll moved after pointwise
//  - per-wave flag bytes: each wave drains its own stores then signals
// h rings: depth 8 (slack), coalesced sc0sc1 bypass loads, counted vmcnt.
__global__ __attribute__((amdgpu_flat_work_group_size(512, 512), amdgpu_waves_per_eu(2, 2)))
void k_persist(const f16* __restrict__ x16,
               const f16* __restrict__ W0f, const float* __restrict__ b0r,
               const f16* __restrict__ W1f, const float* __restrict__ b1r,
               f16* __restrict__ h0buf, f16* __restrict__ h1buf,
               f16* __restrict__ h1all, unsigned char* flags8) {
  const int layer = blockIdx.x >> 7;
  const int sub = blockIdx.x & 127;
  const int rh = sub >> 6, jc = sub & 63;

  __shared__ float cred[8][32][69];

  const int tid = threadIdx.x;
  const int w = tid >> 6, lane = tid & 63;
  const int l15 = lane & 15, q8 = (lane >> 4) << 3;
  const int rbase = rh * 32;
  const int m = tid >> 4, jl = tid & 15;

  // flag sets: (layer,rh) -> 64 blocks x 8 waves = 512 bytes, contiguous
  const int SET0 = rh * 512;
  const int SET1 = (2 + rh) * 512;
  unsigned char* myflag = flags8 + (layer * 2 + rh) * 512 + jc * 8 + w;

  const float* bias = (layer ? b1r : b0r) + jc * 64;
  const float bI = bias[jl], bF = bias[16 + jl], bG = bias[32 + jl], bO = bias[48 + jl];
  float creg = 0.f;

#define POLLW(SOFF, NEEDV)                                                               \
  {                                                                                      \
    int needI = (NEEDV); if (needI < 0) needI = 0;                                       \
    unsigned int nb = (unsigned int)needI & 255u;                                        \
    const unsigned long long* fp_ =                                                      \
        (const unsigned long long*)(flags8 + (SOFF)) + lane;                             \
    for (;;) {                                                                           \
      unsigned long long v_;                                                             \
      asm volatile("global_load_dwordx2 %0, %1, off sc0 sc1\n\ts_waitcnt vmcnt(0)"       \
                   : "=&v"(v_) : "v"(fp_) : "memory");                                   \
      unsigned int ok = 1u;                                                              \
      _Pragma("unroll") for (int b_ = 0; b_ < 8; ++b_) {                                 \
        unsigned int bv = (unsigned int)(v_ >> (b_ * 8)) & 255u;                         \
        ok &= (((bv - nb) & 255u) < 128u);                                               \
      }                                                                                  \
      if (__all(ok)) break;                                                              \
      __builtin_amdgcn_s_sleep(1);                                                       \
    }                                                                                    \
  }

#define CRED_AND_POINTWISE(HOUT, HALL, PRESTORE)                                         \
  {                                                                                      \
    _Pragma("unroll") for (int rf = 0; rf < 2; ++rf)                                     \
      _Pragma("unroll") for (int cf = 0; cf < 4; ++cf)                                   \
        _Pragma("unroll") for (int r = 0; r < 4; ++r)                                    \
          cred[w][rf * 16 + (lane >> 4) * 4 + r][cf * 16 + l15] = acc[rf][cf][r];        \
    __syncthreads();                                                                     \
    float ip = bI, fp = bF, gp2 = bG, op = bO;                                           \
    _Pragma("unroll") for (int ww = 0; ww < 8; ++ww) {                                   \
      ip += cred[ww][m][jl];                                                             \
      fp += cred[ww][m][16 + jl];                                                        \
      gp2 += cred[ww][m][32 + jl];                                                       \
      op += cred[ww][m][48 + jl];                                                        \
    }                                                                                    \
    float ig = 1.f / (1.f + __expf(-ip));                                                \
    float fg = 1.f / (1.f + __expf(-fp));                                                \
    float ea = __expf(-2.f * fabsf(gp2));                                                \
    float gg = copysignf((1.f - ea) / (1.f + ea), gp2);                                  \
    float og = 1.f / (1.f + __expf(-op));                                                \
    creg = fg * creg + ig * gg;                                                          \
    float eb = __expf(-2.f * fabsf(creg));                                               \
    float hval = og * copysignf((1.f - eb) / (1.f + eb), creg);                          \
    PRESTORE                                                                             \
    size_t idx = (size_t)(rbase + m) * 1024 + jc * 16 + jl;                              \
    union { f16 h; unsigned short s; } cv; cv.h = (f16)hval;                             \
    __hip_atomic_store((unsigned short*)((HOUT) + idx), cv.s,                            \
                       __ATOMIC_RELAXED, __HIP_MEMORY_SCOPE_AGENT);                      \
    if (HALL) ((f16*)(HALL))[idx] = cv.h;                                                \
    asm volatile("s_waitcnt vmcnt(0)" ::: "memory");                                     \
    if (lane == 0) {                                                                     \
      unsigned int fv = (unsigned int)(t + 1) & 255u;                                    \
      asm volatile("global_store_byte %0, %1, off sc0 sc1" ::                            \
                   "v"(myflag), "v"(fv) : "memory");                                     \
    }                                                                                    \
    __syncthreads(); /* protects cred against next-step WAR */                           \
  }

#define GLD_X(dst, addr)                                                                 \
  asm volatile("global_load_dwordx4 %0, %1, off sc0 sc1" : "=&v"(dst) : "v"(addr) : "memory")
#define GLD_C(dst, addr)                                                                 \
  asm volatile("global_load_dwordx4 %0, %1, off" : "=&v"(dst) : "v"(addr) : "memory")
#define WAITV(n)                                                                         \
  { asm volatile("s_waitcnt vmcnt(" #n ")" ::: "memory"); __builtin_amdgcn_sched_barrier(0); }

  if (layer == 0) {
    const int KK = 6;
    f16x8 wreg[6][4];
#pragma unroll
    for (int kk = 0; kk < KK; ++kk)
#pragma unroll
      for (int cf = 0; cf < 4; ++cf)
        wreg[kk][cf] = *(const f16x8*)(W0f + ((size_t)((jc * 8 + w) * KK + kk) * 4 + cf) * 512 + lane * 8);
#pragma unroll
    for (int kk = 0; kk < KK; ++kk)
      asm volatile("" : "+v"(wreg[kk][0]), "+v"(wreg[kk][1]), "+v"(wreg[kk][2]), "+v"(wreg[kk][3]));

    for (int t = 0; t < 512; ++t) {
      const f16* A0x = x16 + (size_t)t * 32768;
      const f16* A1h = h0buf + (size_t)((t + 7) & 7) * 65536;  // h0_{t-1}
      f16* hout = h0buf + (size_t)(t & 7) * 65536;             // h0_t

      f16x8 af[6][2];
#define ISSUE_X(kk)                                                                      \
      {                                                                                  \
        int k_ = w * 64 + (kk) * 32 + q8;                                                \
        const f16* ap_ = A0x + k_;                                                       \
        GLD_C(af[kk][0], ap_ + (size_t)(rbase + l15) * 512);                             \
        GLD_C(af[kk][1], ap_ + (size_t)(rbase + 16 + l15) * 512);                        \
      }
#define ISSUE_H0(kk)                                                                     \
      {                                                                                  \
        int hk_ = w * 128 + ((kk) - 2) * 32 + q8;                                        \
        const f16* ap_ = A1h + hk_;                                                      \
        GLD_X(af[kk][0], ap_ + (size_t)(rbase + l15) * 1024);                            \
        GLD_X(af[kk][1], ap_ + (size_t)(rbase + 16 + l15) * 1024);                       \
      }
#define MF0(kk)                                                                          \
      { _Pragma("unroll") for (int rf = 0; rf < 2; ++rf)                                 \
          _Pragma("unroll") for (int cf = 0; cf < 4; ++cf)                               \
            acc[rf][cf] = MFMA16(af[kk][rf], wreg[kk][cf], acc[rf][cf]); }

      f32x4 acc[2][4];
#pragma unroll
      for (int i = 0; i < 2; ++i)
#pragma unroll
        for (int j = 0; j < 4; ++j) acc[i][j] = f32x4{0.f, 0.f, 0.f, 0.f};

      ISSUE_X(0) ISSUE_X(1)          // x loads: flag-independent, issued pre-poll
      POLLW(SET0, t);                // h0_{t-1} ready (drains x loads too)
      ISSUE_H0(2) ISSUE_H0(3) ISSUE_H0(4) ISSUE_H0(5)
      MF0(0) MF0(1)                  // x data already drained by the poll
      WAITV(6) MF0(2)
      WAITV(4) MF0(3)
      WAITV(2) MF0(4)
      WAITV(0) MF0(5)
#undef ISSUE_X
#undef ISSUE_H0
#undef MF0

      CRED_AND_POINTWISE(hout, (f16*)nullptr, POLLW(SET1, t - 7);)
    }
  } else {
    const int KK = 8;
    f16x8 wreg[8][4];
#pragma unroll
    for (int kk = 0; kk < KK; ++kk)
#pragma unroll
      for (int cf = 0; cf < 4; ++cf)
        wreg[kk][cf] = *(const f16x8*)(W1f + ((size_t)((jc * 8 + w) * KK + kk) * 4 + cf) * 512 + lane * 8);
#pragma unroll
    for (int kk = 0; kk < KK; ++kk)
      asm volatile("" : "+v"(wreg[kk][0]), "+v"(wreg[kk][1]), "+v"(wreg[kk][2]), "+v"(wreg[kk][3]));

    for (int t = 0; t < 512; ++t) {
      const f16* A0 = h0buf + (size_t)(t & 7) * 65536;         // h0_t
      const f16* A1 = h1buf + (size_t)((t + 7) & 7) * 65536;   // h1_{t-1}
      f16* hout = h1buf + (size_t)(t & 7) * 65536;             // h1_t
      f16* hall = h1all + (size_t)t * 65536;

      f16x8 af[8][2];
#define ISSUE_HH(kk, BASE)                                                               \
      {                                                                                  \
        int hk_ = w * 128 + ((kk) & 3) * 32 + q8;                                        \
        const f16* ap_ = (BASE) + hk_;                                                   \
        GLD_X(af[kk][0], ap_ + (size_t)(rbase + l15) * 1024);                            \
        GLD_X(af[kk][1], ap_ + (size_t)(rbase + 16 + l15) * 1024);                       \
      }
#define MF1(kk)                                                                          \
      { _Pragma("unroll") for (int rf = 0; rf < 2; ++rf)                                 \
          _Pragma("unroll") for (int cf = 0; cf < 4; ++cf)                               \
            acc[rf][cf] = MFMA16(af[kk][rf], wreg[kk][cf], acc[rf][cf]); }

      f32x4 acc[2][4];
#pragma unroll
      for (int i = 0; i < 2; ++i)
#pragma unroll
        for (int j = 0; j < 4; ++j) acc[i][j] = f32x4{0.f, 0.f, 0.f, 0.f};

      POLLW(SET1, t);                         // h1_{t-1} ready (own-layer lockstep)
      ISSUE_HH(4, A1) ISSUE_HH(5, A1) ISSUE_HH(6, A1) ISSUE_HH(7, A1)
      POLLW(SET0, t + 1);                     // h0_t (usually pre-satisfied; drains h1)
      ISSUE_HH(0, A0) ISSUE_HH(1, A0)
      MF1(4) MF1(5)                           // h1 data drained by poll0
      ISSUE_HH(2, A0) ISSUE_HH(3, A0)
      MF1(6) MF1(7)
      WAITV(6) MF1(0)
      WAITV(4) MF1(1)
      WAITV(2) MF1(2)
      WAITV(0) MF1(3)
#undef ISSUE_HH
#undef MF1

      CRED_AND_POINTWISE(hout, hall, ;)
    }
  }
#undef POLLW
#undef CRED_AND_POINTWISE
#undef GLD_X
#undef GLD_C
#undef WAITV
}

// ---------------- final FC ----------------
__global__ __launch_bounds__(512, 1)
void k_fc(const f16* __restrict__ h1all, const f16* __restrict__ Wfc16,
          const float* __restrict__ bfc, float* __restrict__ out) {
  const int s = blockIdx.x;
  const f16* A = h1all + (size_t)s * 65536;
  __shared__ float credf[8][64][68];

  const int w = threadIdx.x >> 6;
  const int lane = threadIdx.x & 63;
  const int l15 = lane & 15;
  const int ksub = (lane >> 4) << 3;

  f32x4 acc[4][4];
#pragma unroll
  for (int i = 0; i < 4; ++i)
#pragma unroll
    for (int j = 0; j < 4; ++j) acc[i][j] = f32x4{0.f, 0.f, 0.f, 0.f};

  const int kbeg = w * 128, kend = kbeg + 128;
  f16x8 af0[4], bf0[4], af1[4], bf1[4];

  auto LOADK = [&](int kc, f16x8(&a)[4], f16x8(&b)[4]) {
    const f16* ap = A + kc + ksub;
#pragma unroll
    for (int rf = 0; rf < 4; ++rf)
      a[rf] = *(const f16x8*)(ap + (size_t)(rf * 16 + l15) * 1024);
    const f16* bp = Wfc16 + kc + ksub;
#pragma unroll
    for (int cf = 0; cf < 4; ++cf)
      b[cf] = *(const f16x8*)(bp + (size_t)(cf * 16 + l15) * 1024);
  };

  LOADK(kbeg, af0, bf0);
  for (int kc = kbeg; kc < kend; kc += 64) {
    LOADK(kc + 32, af1, bf1);
#pragma unroll
    for (int rf = 0; rf < 4; ++rf)
#pragma unroll
      for (int cf = 0; cf < 4; ++cf) acc[rf][cf] = MFMA16(af0[rf], bf0[cf], acc[rf][cf]);
    if (kc + 64 < kend) LOADK(kc + 64, af0, bf0);
#pragma unroll
    for (int rf = 0; rf < 4; ++rf)
#pragma unroll
      for (int cf = 0; cf < 4; ++cf) acc[rf][cf] = MFMA16(af1[rf], bf1[cf], acc[rf][cf]);
  }

#pragma unroll
  for (int rf = 0; rf < 4; ++rf)
#pragma unroll
    for (int cf = 0; cf < 4; ++cf)
#pragma unroll
      for (int r = 0; r < 4; ++r)
        credf[w][rf * 16 + (lane >> 4) * 4 + r][cf * 16 + l15] = acc[rf][cf][r];

  __syncthreads();

  int m = threadIdx.x >> 3;
  int cbase = (threadIdx.x & 7) * 8;
#pragma unroll
  for (int u = 0; u < 8; ++u) {
    int col = cbase + u;
    float v = bfc[col];
#pragma unroll
    for (int ww = 0; ww < 8; ++ww) v += credf[ww][m][col];
    out[((size_t)m * 512 + s) * 64 + col] = v;
  }
}

// ---------------- host ----------------
extern "C" void kernel_launch(void* const* d_in, const int* in_sizes, int n_in,
                              void* d_out, int out_size, void* d_ws, size_t ws_size,
                              hipStream_t stream) {
  const float* x    = (const float*)d_in[0];
  const float* Wih0 = (const float*)d_in[1];
  const float* Whh0 = (const float*)d_in[2];
  const float* bih0 = (const float*)d_in[3];
  const float* bhh0 = (const float*)d_in[4];
  const float* Wih1 = (const float*)d_in[5];
  const float* Whh1 = (const float*)d_in[6];
  const float* bih1 = (const float*)d_in[7];
  const float* bhh1 = (const float*)d_in[8];
  const float* Wfc  = (const float*)d_in[9];
  const float* bfc  = (const float*)d_in[10];
  float* out = (float*)d_out;

  char* ws = (char*)d_ws;
  f16*   W0f   = (f16*)(ws + 0);           // 12,582,912
  f16*   W1f   = (f16*)(ws + 12582912);    // 16,777,216 -> 29,360,128
  f16*   Wfc16 = (f16*)(ws + 29360128);    // 131,072   -> 29,491,200
  float* b0r   = (float*)(ws + 29491200);  // 16,384    -> 29,507,584
  float* b1r   = (float*)(ws + 29507584);  // 16,384    -> 29,523,968
  f16*   x16   = (f16*)(ws + 29523968);    // 33,554,432 -> 63,078,400
  f16*   h1all = (f16*)(ws + 63078400);    // 67,108,864 -> 130,187,264
  f16*   h0buf = (f16*)(ws + 130187264);   // 8 * 131,072 = 1,048,576 -> 131,235,840
  f16*   h1buf = (f16*)(ws + 131235840);   // 1,048,576 -> 132,284,416
  unsigned char* flags8 = (unsigned char*)(ws + 132284416);  // 2,048 B

  k_conv_x<<<8192, 256, 0, stream>>>(x, x16);
  k_conv_wfrag<<<12288, 64, 0, stream>>>(Wih0, Whh0, W0f, 512, 6, 0);
  k_conv_wfrag<<<16384, 64, 0, stream>>>(Wih1, Whh1, W1f, 1024, 8, 1);
  k_conv_bias<<<64, 64, 0, stream>>>(bih0, bhh0, b0r);
  k_conv_bias<<<64, 64, 0, stream>>>(bih1, bhh1, b1r);
  k_conv_wfc<<<256, 256, 0, stream>>>(Wfc, Wfc16);
  // zero h rings + flags every launch (graph-replay determinism)
  hipMemsetAsync(ws + 130187264, 0, 1048576 * 2 + 2048, stream);

  {
    const f16* x16c = x16; const f16* W0fc = W0f; const float* b0rc = b0r;
    const f16* W1fc = W1f; const float* b1rc = b1r;
    f16 *p0 = h0buf, *p1 = h1buf, *ph = h1all;
    unsigned char* fl = flags8;
    void* kargs[] = { &x16c, &W0fc, &b0rc, &W1fc, &b1rc, &p0, &p1, &ph, &fl };
    hipLaunchCooperativeKernel((void*)k_persist, dim3(256), dim3(512), kargs, 0, stream);
  }

  k_fc<<<512, 512, 0, stream>>>(h1all, Wfc16, bfc, out);
}

// Round 13
// 4836.516 us; speedup vs baseline: 2.4891x; 2.4891x over previous
//
#include <hip/hip_runtime.h>
#include <stdint.h>

typedef _Float16 f16;
typedef _Float16 f16x8 __attribute__((ext_vector_type(8)));
typedef float f32x4 __attribute__((ext_vector_type(4)));

#define MFMA16(a, b, c) __builtin_amdgcn_mfma_f32_16x16x32_f16((a), (b), (c), 0, 0, 0)

// Sizes: B=64, S=512, I=512, H=1024, 4H=4096, O=64

// ---------------- prep kernels ----------------

__global__ void k_conv_x(const float* __restrict__ x, f16* __restrict__ x16) {
  int i = blockIdx.x * 256 + threadIdx.x;
  int o = i * 8;
  int s = o >> 15, b = (o >> 9) & 63, c = o & 511;
  const float* src = x + (size_t)b * 262144 + (size_t)s * 512 + c;
  float4 v0 = *(const float4*)(src);
  float4 v1 = *(const float4*)(src + 4);
  union { f16 h[8]; f16x8 v; } t;
  t.h[0] = (f16)v0.x; t.h[1] = (f16)v0.y; t.h[2] = (f16)v0.z; t.h[3] = (f16)v0.w;
  t.h[4] = (f16)v1.x; t.h[5] = (f16)v1.y; t.h[6] = (f16)v1.z; t.h[7] = (f16)v1.w;
  *(f16x8*)(x16 + o) = t.v;
}

// Weights -> per-(colgroup,wave,kk,cf) MFMA B-fragments, f32->f16.
// fid = ((jc*8 + w)*KK + kk)*4 + cf. Lane holds W[c][k..k+7]:
//   slab col c = cf*16 + (lane&15) -> gate row g = (c>>4)*1024 + jc*16 + (c&15)
// K mapping: mode0 (L0): kk<2 -> k = w*64+kk*32 (x part); kk>=2 -> 512+w*128+(kk-2)*32
//            mode1 (L1): k = w*256 + kk*32 (contiguous; waves 0-3 h0, 4-7 h1)
__global__ void k_conv_wfrag(const float* __restrict__ Wih, const float* __restrict__ Whh,
                             f16* __restrict__ Wf, int KI, int KK, int mode) {
  int fid = blockIdx.x;
  int lane = threadIdx.x;
  int cf = fid & 3; int rest = fid >> 2;
  int kk = rest % KK; rest /= KK; int w = rest & 7; int jc = rest >> 3;
  int c = cf * 16 + (lane & 15);
  int g = (c >> 4) * 1024 + jc * 16 + (c & 15);
  int k = (mode == 0)
              ? ((kk < 2) ? (w * 64 + kk * 32) : (512 + w * 128 + (kk - 2) * 32))
              : (w * 256 + kk * 32);
  k += (lane >> 4) << 3;
  const float* src = (k < KI) ? (Wih + (size_t)g * KI + k)
                              : (Whh + (size_t)g * 1024 + (k - KI));
  union { f16 h[8]; f16x8 v; } t;
#pragma unroll
  for (int i = 0; i < 8; ++i) t.h[i] = (f16)src[i];
  *(f16x8*)(Wf + ((size_t)fid * 64 + lane) * 8) = t.v;
}

__global__ void k_conv_bias(const float* __restrict__ bih, const float* __restrict__ bhh,
                            float* __restrict__ br) {
  int d = blockIdx.x * 64 + threadIdx.x;  // 4096: d = jc*64 + c
  int jc = d >> 6, c = d & 63;
  int g = (c >> 4) * 1024 + jc * 16 + (c & 15);
  br[d] = bih[g] + bhh[g];
}

__global__ void k_conv_wfc(const float* __restrict__ Wfc, f16* __restrict__ Wfc16) {
  int i = blockIdx.x * 256 + threadIdx.x;
  Wfc16[i] = (f16)Wfc[i];
}

// ---------------- persistent pipelined LSTM ----------------
// 256 blocks x 512 threads, cooperative, 1 block/CU. layer = bid>>7;
// sub = bid&127; rh = sub>>6 (32-row half), jc = sub&63 (16 h-cols).
// Weights in registers. h rings depth 4, coalesced sc0sc1 bypass loads,
// counted-vmcnt pipeline. Sync (measured-optimal family): wave-0-only poll
// of ONE 128B line = the two same-rh 64-flag byte sets, then barrier.
// L0 K-remap gives every wave pure-x slices issued BEFORE the poll.
__global__ __attribute__((amdgpu_flat_work_group_size(512, 512), amdgpu_waves_per_eu(2, 2)))
void k_persist(const f16* __restrict__ x16,
               const f16* __restrict__ W0f, const float* __restrict__ b0r,
               const f16* __restrict__ W1f, const float* __restrict__ b1r,
               f16* __restrict__ h0buf, f16* __restrict__ h1buf,
               f16* __restrict__ h1all, unsigned char* flags8) {
  const int layer = blockIdx.x >> 7;
  const int sub = blockIdx.x & 127;
  const int rh = sub >> 6, jc = sub & 63;

  __shared__ float cred[8][32][66];  // stride 66: write phase uniform 2-way (free)

  // flags8[rh*128 + layer*64 + jc]: both sets a block needs share ONE 128B line
  unsigned char* myflag = flags8 + rh * 128 + layer * 64 + jc;

  const int tid = threadIdx.x;
  const int w = tid >> 6, lane = tid & 63;
  const int l15 = lane & 15, q8 = (lane >> 4) << 3;
  const int rbase = rh * 32;
  const int m = tid >> 4, jl = tid & 15;

  const float* bias = (layer ? b1r : b0r) + jc * 64;
  const float bI = bias[jl], bF = bias[16 + jl], bG = bias[32 + jl], bO = bias[48 + jl];
  float creg = 0.f;

#define POLLG(n0v, n1v)                                                                  \
  {                                                                                      \
    if (w == 0) {                                                                        \
      int li = lane & 31;                                                                \
      int needI = (li < 16) ? (n0v) : (n1v);                                             \
      if (needI < 0) needI = 0;                                                          \
      unsigned int nb = (unsigned int)needI & 255u;                                      \
      const unsigned int* fp_ = (const unsigned int*)(flags8 + rh * 128) + li;           \
      for (;;) {                                                                         \
        unsigned int v_;                                                                 \
        asm volatile("global_load_dword %0, %1, off sc0 sc1\n\ts_waitcnt vmcnt(0)"       \
                     : "=&v"(v_) : "v"(fp_) : "memory");                                 \
        unsigned int ok = (((v_ & 255u) - nb) & 255u) < 128u;                            \
        ok &= ((((v_ >> 8) & 255u) - nb) & 255u) < 128u;                                 \
        ok &= ((((v_ >> 16) & 255u) - nb) & 255u) < 128u;                                \
        ok &= ((((v_ >> 24) & 255u) - nb) & 255u) < 128u;                                \
        if (__all(ok)) break;                                                            \
        __builtin_amdgcn_s_sleep(1);                                                     \
      }                                                                                  \
    }                                                                                    \
    __syncthreads();                                                                     \
  }

#define CRED_AND_POINTWISE(HOUT, HALL)                                                   \
  {                                                                                      \
    _Pragma("unroll") for (int rf = 0; rf < 2; ++rf)                                     \
      _Pragma("unroll") for (int cf = 0; cf < 4; ++cf)                                   \
        _Pragma("unroll") for (int r = 0; r < 4; ++r)                                    \
          cred[w][rf * 16 + (lane >> 4) * 4 + r][cf * 16 + l15] = acc[rf][cf][r];        \
    __syncthreads();                                                                     \
    float ip = bI, fp = bF, gp2 = bG, op = bO;                                           \
    _Pragma("unroll") for (int ww = 0; ww < 8; ++ww) {                                   \
      ip += cred[ww][m][jl];                                                             \
      fp += cred[ww][m][16 + jl];                                                        \
      gp2 += cred[ww][m][32 + jl];                                                       \
      op += cred[ww][m][48 + jl];                                                        \
    }                                                                                    \
    float ig = 1.f / (1.f + __expf(-ip));                                                \
    float fg = 1.f / (1.f + __expf(-fp));                                                \
    float ea = __expf(-2.f * fabsf(gp2));                                                \
    float gg = copysignf((1.f - ea) / (1.f + ea), gp2);                                  \
    float og = 1.f / (1.f + __expf(-op));                                                \
    creg = fg * creg + ig * gg;                                                          \
    float eb = __expf(-2.f * fabsf(creg));                                               \
    float hval = og * copysignf((1.f - eb) / (1.f + eb), creg);                          \
    size_t idx = (size_t)(rbase + m) * 1024 + jc * 16 + jl;                              \
    union { f16 h; unsigned short s; } cv; cv.h = (f16)hval;                             \
    __hip_atomic_store((unsigned short*)((HOUT) + idx), cv.s,                            \
                       __ATOMIC_RELAXED, __HIP_MEMORY_SCOPE_AGENT);                      \
    if (HALL) ((f16*)(HALL))[idx] = cv.h;                                                \
    __syncthreads(); /* drains vmcnt(0) per wave: all h stores ack'd */                  \
    if (tid == 0) {                                                                      \
      unsigned int fv = (unsigned int)(t + 1) & 255u;                                    \
      asm volatile("global_store_byte %0, %1, off sc0 sc1" ::                            \
                   "v"(myflag), "v"(fv) : "memory");                                     \
    }                                                                                    \
  }

#define GLD_X(dst, addr)                                                                 \
  asm volatile("global_load_dwordx4 %0, %1, off sc0 sc1" : "=&v"(dst) : "v"(addr) : "memory")
#define GLD_C(dst, addr)                                                                 \
  asm volatile("global_load_dwordx4 %0, %1, off" : "=&v"(dst) : "v"(addr) : "memory")
#define WAITV(n)                                                                         \
  { asm volatile("s_waitcnt vmcnt(" #n ")" ::: "memory"); __builtin_amdgcn_sched_barrier(0); }

  if (layer == 0) {
    const int KK = 6;
    f16x8 wreg[6][4];
#pragma unroll
    for (int kk = 0; kk < KK; ++kk)
#pragma unroll
      for (int cf = 0; cf < 4; ++cf)
        wreg[kk][cf] = *(const f16x8*)(W0f + ((size_t)((jc * 8 + w) * KK + kk) * 4 + cf) * 512 + lane * 8);
#pragma unroll
    for (int kk = 0; kk < KK; ++kk)
      asm volatile("" : "+v"(wreg[kk][0]), "+v"(wreg[kk][1]), "+v"(wreg[kk][2]), "+v"(wreg[kk][3]));

    for (int t = 0; t < 512; ++t) {
      const f16* A0x = x16 + (size_t)t * 32768;
      const f16* A1h = h0buf + (size_t)((t + 3) & 3) * 65536;  // h0_{t-1}
      f16* hout = h0buf + (size_t)(t & 3) * 65536;             // h0_t

      f16x8 af[6][2];
#define ISSUE_X(kk)                                                                      \
      {                                                                                  \
        int k_ = w * 64 + (kk) * 32 + q8;                                                \
        const f16* ap_ = A0x + k_;                                                       \
        GLD_C(af[kk][0], ap_ + (size_t)(rbase + l15) * 512);                             \
        GLD_C(af[kk][1], ap_ + (size_t)(rbase + 16 + l15) * 512);                        \
      }
#define ISSUE_H0(kk)                                                                     \
      {                                                                                  \
        int hk_ = w * 128 + ((kk) - 2) * 32 + q8;                                        \
        const f16* ap_ = A1h + hk_;                                                      \
        GLD_X(af[kk][0], ap_ + (size_t)(rbase + l15) * 1024);                            \
        GLD_X(af[kk][1], ap_ + (size_t)(rbase + 16 + l15) * 1024);                       \
      }
#define MF0(kk)                                                                          \
      { _Pragma("unroll") for (int rf = 0; rf < 2; ++rf)                                 \
          _Pragma("unroll") for (int cf = 0; cf < 4; ++cf)                               \
            acc[rf][cf] = MFMA16(af[kk][rf], wreg[kk][cf], acc[rf][cf]); }

      f32x4 acc[2][4];
#pragma unroll
      for (int i = 0; i < 2; ++i)
#pragma unroll
        for (int j = 0; j < 4; ++j) acc[i][j] = f32x4{0.f, 0.f, 0.f, 0.f};

      ISSUE_X(0) ISSUE_X(1)          // pure-x slices: flag-independent, all waves
      POLLG(t, t - 3);               // h0_{t-1} ready + WAR(L1 >= t-3); 1-line poll
      ISSUE_H0(2) ISSUE_H0(3) ISSUE_H0(4) ISSUE_H0(5)
      WAITV(8)  MF0(0) MF0(1)        // x loads retired (12 outstanding -> 8)
      WAITV(6)  MF0(2)
      WAITV(4)  MF0(3)
      WAITV(2)  MF0(4)
      WAITV(0)  MF0(5)
#undef ISSUE_X
#undef ISSUE_H0
#undef MF0

      CRED_AND_POINTWISE(hout, (f16*)nullptr);
    }
  } else {
    const int KK = 8;
    f16x8 wreg[8][4];
#pragma unroll
    for (int kk = 0; kk < KK; ++kk)
#pragma unroll
      for (int cf = 0; cf < 4; ++cf)
        wreg[kk][cf] = *(const f16x8*)(W1f + ((size_t)((jc * 8 + w) * KK + kk) * 4 + cf) * 512 + lane * 8);
#pragma unroll
    for (int kk = 0; kk < KK; ++kk)
      asm volatile("" : "+v"(wreg[kk][0]), "+v"(wreg[kk][1]), "+v"(wreg[kk][2]), "+v"(wreg[kk][3]));

    const int kbeg = w * 256;
    for (int t = 0; t < 512; ++t) {
      const f16* A0 = h0buf + (size_t)(t & 3) * 65536;        // h0_t
      const f16* A1 = h1buf + (size_t)((t + 3) & 3) * 65536;  // h1_{t-1}
      f16* hout = h1buf + (size_t)(t & 3) * 65536;            // h1_t
      f16* hall = h1all + (size_t)t * 65536;

      POLLG(t + 1, t);

      f16x8 af[4][2];
#define ISSUE1(kk)                                                                       \
      {                                                                                  \
        int k_ = kbeg + (kk) * 32 + q8;                                                  \
        const f16* ap_ = (k_ < 1024) ? (A0 + k_) : (A1 + (k_ - 1024));                   \
        GLD_X(af[(kk) & 3][0], ap_ + (size_t)(rbase + l15) * 1024);                      \
        GLD_X(af[(kk) & 3][1], ap_ + (size_t)(rbase + 16 + l15) * 1024);                 \
      }
#define MF1(kk)                                                                          \
      { _Pragma("unroll") for (int rf = 0; rf < 2; ++rf)                                 \
          _Pragma("unroll") for (int cf = 0; cf < 4; ++cf)                               \
            acc[rf][cf] = MFMA16(af[(kk) & 3][rf], wreg[kk][cf], acc[rf][cf]); }

      f32x4 acc[2][4];
#pragma unroll
      for (int i = 0; i < 2; ++i)
#pragma unroll
        for (int j = 0; j < 4; ++j) acc[i][j] = f32x4{0.f, 0.f, 0.f, 0.f};

      ISSUE1(0) ISSUE1(1) ISSUE1(2) ISSUE1(3)
      WAITV(6) MF1(0) ISSUE1(4)
      WAITV(6) MF1(1) ISSUE1(5)
      WAITV(6) MF1(2) ISSUE1(6)
      WAITV(6) MF1(3) ISSUE1(7)
      WAITV(6) MF1(4)
      WAITV(4) MF1(5)
      WAITV(2) MF1(6)
      WAITV(0) MF1(7)
#undef ISSUE1
#undef MF1

      CRED_AND_POINTWISE(hout, hall);
    }
  }
#undef POLLG
#undef CRED_AND_POINTWISE
#undef GLD_X
#undef GLD_C
#undef WAITV
}

// ---------------- final FC ----------------
__global__ __launch_bounds__(512, 1)
void k_fc(const f16* __restrict__ h1all, const f16* __restrict__ Wfc16,
          const float* __restrict__ bfc, float* __restrict__ out) {
  const int s = blockIdx.x;
  const f16* A = h1all + (size_t)s * 65536;
  __shared__ float credf[8][64][68];

  const int w = threadIdx.x >> 6;
  const int lane = threadIdx.x & 63;
  const int l15 = lane & 15;
  const int ksub = (lane >> 4) << 3;

  f32x4 acc[4][4];
#pragma unroll
  for (int i = 0; i < 4; ++i)
#pragma unroll
    for (int j = 0; j < 4; ++j) acc[i][j] = f32x4{0.f, 0.f, 0.f, 0.f};

  const int kbeg = w * 128, kend = kbeg + 128;
  f16x8 af0[4], bf0[4], af1[4], bf1[4];

  auto LOADK = [&](int kc, f16x8(&a)[4], f16x8(&b)[4]) {
    const f16* ap = A + kc + ksub;
#pragma unroll
    for (int rf = 0; rf < 4; ++rf)
      a[rf] = *(const f16x8*)(ap + (size_t)(rf * 16 + l15) * 1024);
    const f16* bp = Wfc16 + kc + ksub;
#pragma unroll
    for (int cf = 0; cf < 4; ++cf)
      b[cf] = *(const f16x8*)(bp + (size_t)(cf * 16 + l15) * 1024);
  };

  LOADK(kbeg, af0, bf0);
  for (int kc = kbeg; kc < kend; kc += 64) {
    LOADK(kc + 32, af1, bf1);
#pragma unroll
    for (int rf = 0; rf < 4; ++rf)
#pragma unroll
      for (int cf = 0; cf < 4; ++cf) acc[rf][cf] = MFMA16(af0[rf], bf0[cf], acc[rf][cf]);
    if (kc + 64 < kend) LOADK(kc + 64, af0, bf0);
#pragma unroll
    for (int rf = 0; rf < 4; ++rf)
#pragma unroll
      for (int cf = 0; cf < 4; ++cf) acc[rf][cf] = MFMA16(af1[rf], bf1[cf], acc[rf][cf]);
  }

#pragma unroll
  for (int rf = 0; rf < 4; ++rf)
#pragma unroll
    for (int cf = 0; cf < 4; ++cf)
#pragma unroll
      for (int r = 0; r < 4; ++r)
        credf[w][rf * 16 + (lane >> 4) * 4 + r][cf * 16 + l15] = acc[rf][cf][r];

  __syncthreads();

  int m = threadIdx.x >> 3;
  int cbase = (threadIdx.x & 7) * 8;
#pragma unroll
  for (int u = 0; u < 8; ++u) {
    int col = cbase + u;
    float v = bfc[col];
#pragma unroll
    for (int ww = 0; ww < 8; ++ww) v += credf[ww][m][col];
    out[((size_t)m * 512 + s) * 64 + col] = v;
  }
}

// ---------------- host ----------------
extern "C" void kernel_launch(void* const* d_in, const int* in_sizes, int n_in,
                              void* d_out, int out_size, void* d_ws, size_t ws_size,
                              hipStream_t stream) {
  const float* x    = (const float*)d_in[0];
  const float* Wih0 = (const float*)d_in[1];
  const float* Whh0 = (const float*)d_in[2];
  const float* bih0 = (const float*)d_in[3];
  const float* bhh0 = (const float*)d_in[4];
  const float* Wih1 = (const float*)d_in[5];
  const float* Whh1 = (const float*)d_in[6];
  const float* bih1 = (const float*)d_in[7];
  const float* bhh1 = (const float*)d_in[8];
  const float* Wfc  = (const float*)d_in[9];
  const float* bfc  = (const float*)d_in[10];
  float* out = (float*)d_out;

  char* ws = (char*)d_ws;
  f16*   W0f   = (f16*)(ws + 0);           // 12,582,912
  f16*   W1f   = (f16*)(ws + 12582912);    // 16,777,216 -> 29,360,128
  f16*   Wfc16 = (f16*)(ws + 29360128);    // 131,072   -> 29,491,200
  float* b0r   = (float*)(ws + 29491200);  // 16,384    -> 29,507,584
  float* b1r   = (float*)(ws + 29507584);  // 16,384    -> 29,523,968
  f16*   x16   = (f16*)(ws + 29523968);    // 33,554,432 -> 63,078,400
  f16*   h1all = (f16*)(ws + 63078400);    // 67,108,864 -> 130,187,264
  f16*   h0buf = (f16*)(ws + 130187264);   // 524,288   -> 130,711,552
  f16*   h1buf = (f16*)(ws + 130711552);   // 524,288   -> 131,235,840
  unsigned char* flags8 = (unsigned char*)(ws + 131235840);  // 256 B

  k_conv_x<<<8192, 256, 0, stream>>>(x, x16);
  k_conv_wfrag<<<12288, 64, 0, stream>>>(Wih0, Whh0, W0f, 512, 6, 0);
  k_conv_wfrag<<<16384, 64, 0, stream>>>(Wih1, Whh1, W1f, 1024, 8, 1);
  k_conv_bias<<<64, 64, 0, stream>>>(bih0, bhh0, b0r);
  k_conv_bias<<<64, 64, 0, stream>>>(bih1, bhh1, b1r);
  k_conv_wfc<<<256, 256, 0, stream>>>(Wfc, Wfc16);
  // zero h rings + flags every launch (graph-replay determinism)
  hipMemsetAsync(ws + 130187264, 0, 524288 * 2 + 256, stream);

  {
    const f16* x16c = x16; const f16* W0fc = W0f; const float* b0rc = b0r;
    const f16* W1fc = W1f; const float* b1rc = b1r;
    f16 *p0 = h0buf, *p1 = h1buf, *ph = h1all;
    unsigned char* fl = flags8;
    void* kargs[] = { &x16c, &W0fc, &b0rc, &W1fc, &b1rc, &p0, &p1, &ph, &fl };
    hipLaunchCooperativeKernel((void*)k_persist, dim3(256), dim3(512), kargs, 0, stream);
  }

  k_fc<<<512, 512, 0, stream>>>(h1all, Wfc16, bfc, out);
}

// Round 14
// 4688.888 us; speedup vs baseline: 2.5674x; 1.0315x over previous
//
#include <hip/hip_runtime.h>
#include <stdint.h>

typedef _Float16 f16;
typedef _Float16 f16x8 __attribute__((ext_vector_type(8)));
typedef float f32x4 __attribute__((ext_vector_type(4)));

#define MFMA16(a, b, c) __builtin_amdgcn_mfma_f32_16x16x32_f16((a), (b), (c), 0, 0, 0)

// Sizes: B=64, S=512, I=512, H=1024, 4H=4096, O=64

// ---------------- prep kernels ----------------

__global__ void k_conv_x(const float* __restrict__ x, f16* __restrict__ x16) {
  int i = blockIdx.x * 256 + threadIdx.x;
  int o = i * 8;
  int s = o >> 15, b = (o >> 9) & 63, c = o & 511;
  const float* src = x + (size_t)b * 262144 + (size_t)s * 512 + c;
  float4 v0 = *(const float4*)(src);
  float4 v1 = *(const float4*)(src + 4);
  union { f16 h[8]; f16x8 v; } t;
  t.h[0] = (f16)v0.x; t.h[1] = (f16)v0.y; t.h[2] = (f16)v0.z; t.h[3] = (f16)v0.w;
  t.h[4] = (f16)v1.x; t.h[5] = (f16)v1.y; t.h[6] = (f16)v1.z; t.h[7] = (f16)v1.w;
  *(f16x8*)(x16 + o) = t.v;
}

// Weights -> per-(colgroup,wave,kk,cf) MFMA B-fragments, f32->f16.
// fid = ((jc*8 + w)*KK + kk)*4 + cf. Lane holds W[c][k..k+7]:
//   slab col c = cf*16 + (lane&15) -> gate row g = (c>>4)*1024 + jc*16 + (c&15)
// K mapping: mode0 (L0): kk<2 -> k = w*64+kk*32 (x); kk>=2 -> 512+w*128+(kk-2)*32 (h0)
//            mode1 (L1): k = w*256 + kk*32 (waves 0-3 h0-part, 4-7 h1-part)
__global__ void k_conv_wfrag(const float* __restrict__ Wih, const float* __restrict__ Whh,
                             f16* __restrict__ Wf, int KI, int KK, int mode) {
  int fid = blockIdx.x;
  int lane = threadIdx.x;
  int cf = fid & 3; int rest = fid >> 2;
  int kk = rest % KK; rest /= KK; int w = rest & 7; int jc = rest >> 3;
  int c = cf * 16 + (lane & 15);
  int g = (c >> 4) * 1024 + jc * 16 + (c & 15);
  int k = (mode == 0)
              ? ((kk < 2) ? (w * 64 + kk * 32) : (512 + w * 128 + (kk - 2) * 32))
              : (w * 256 + kk * 32);
  k += (lane >> 4) << 3;
  const float* src = (k < KI) ? (Wih + (size_t)g * KI + k)
                              : (Whh + (size_t)g * 1024 + (k - KI));
  union { f16 h[8]; f16x8 v; } t;
#pragma unroll
  for (int i = 0; i < 8; ++i) t.h[i] = (f16)src[i];
  *(f16x8*)(Wf + ((size_t)fid * 64 + lane) * 8) = t.v;
}

__global__ void k_conv_bias(const float* __restrict__ bih, const float* __restrict__ bhh,
                            float* __restrict__ br) {
  int d = blockIdx.x * 64 + threadIdx.x;  // 4096: d = jc*64 + c
  int jc = d >> 6, c = d & 63;
  int g = (c >> 4) * 1024 + jc * 16 + (c & 15);
  br[d] = bih[g] + bhh[g];
}

__global__ void k_conv_wfc(const float* __restrict__ Wfc, f16* __restrict__ Wfc16) {
  int i = blockIdx.x * 256 + threadIdx.x;
  Wfc16[i] = (f16)Wfc[i];
}

// ---------------- persistent pipelined LSTM ----------------
// 256 blocks x 512 threads, cooperative, 1 block/CU. layer = bid>>7;
// sub = bid&127; rh = sub>>6 (32-row half), jc = sub&63 (16 h-cols).
// r11 structure (best measured). Deltas:
//  - h1 ring merged with h1all: 513 slots (slot 0 = zeros); ONE h1 store
//    per step (was two) -> shorter L1 tail, -64MB writes. No h1 WAR.
//  - h0 ring depth 8, L0 WAR poll >= t-7: L0 can lead by 7 -> L0's flag is
//    always pre-satisfied in L1's poll; cadence isolated to L1 RAW chain.
__global__ __attribute__((amdgpu_flat_work_group_size(512, 512), amdgpu_waves_per_eu(2, 2)))
void k_persist(const f16* __restrict__ x16,
               const f16* __restrict__ W0f, const float* __restrict__ b0r,
               const f16* __restrict__ W1f, const float* __restrict__ b1r,
               f16* __restrict__ h0buf, f16* __restrict__ h1ring,
               unsigned char* flags8) {
  const int layer = blockIdx.x >> 7;
  const int sub = blockIdx.x & 127;
  const int rh = sub >> 6, jc = sub & 63;

  __shared__ float cred[8][32][69];

  unsigned char* myflag = flags8 + layer * 128 + sub;

  const int tid = threadIdx.x;
  const int w = tid >> 6, lane = tid & 63;
  const int l15 = lane & 15, q8 = (lane >> 4) << 3;
  const int rbase = rh * 32;
  const int m = tid >> 4, jl = tid & 15;

  const float* bias = (layer ? b1r : b0r) + jc * 64;
  const float bI = bias[jl], bF = bias[16 + jl], bG = bias[32 + jl], bO = bias[48 + jl];
  float creg = 0.f;

#define POLLG(n0v, n1v)                                                                  \
  {                                                                                      \
    if (w == 0) {                                                                        \
      int needI = (lane < 32) ? (n0v) : (n1v);                                           \
      if (needI < 0) needI = 0;                                                          \
      unsigned int nb = (unsigned int)needI & 255u;                                      \
      const unsigned int* fp_ = (const unsigned int*)flags8 + lane;                      \
      for (;;) {                                                                         \
        unsigned int v_;                                                                 \
        asm volatile("global_load_dword %0, %1, off sc0 sc1\n\ts_waitcnt vmcnt(0)"       \
                     : "=&v"(v_) : "v"(fp_) : "memory");                                 \
        unsigned int ok = (((v_ & 255u) - nb) & 255u) < 128u;                            \
        ok &= ((((v_ >> 8) & 255u) - nb) & 255u) < 128u;                                 \
        ok &= ((((v_ >> 16) & 255u) - nb) & 255u) < 128u;                                \
        ok &= ((((v_ >> 24) & 255u) - nb) & 255u) < 128u;                                \
        if (__all(ok)) break;                                                            \
        __builtin_amdgcn_s_sleep(1);                                                     \
      }                                                                                  \
    }                                                                                    \
    __syncthreads();                                                                     \
  }

#define CRED_AND_POINTWISE(HOUT)                                                         \
  {                                                                                      \
    _Pragma("unroll") for (int rf = 0; rf < 2; ++rf)                                     \
      _Pragma("unroll") for (int cf = 0; cf < 4; ++cf)                                   \
        _Pragma("unroll") for (int r = 0; r < 4; ++r)                                    \
          cred[w][rf * 16 + (lane >> 4) * 4 + r][cf * 16 + l15] = acc[rf][cf][r];        \
    __syncthreads();                                                                     \
    float ip = bI, fp = bF, gp2 = bG, op = bO;                                           \
    _Pragma("unroll") for (int ww = 0; ww < 8; ++ww) {                                   \
      ip += cred[ww][m][jl];                                                             \
      fp += cred[ww][m][16 + jl];                                                        \
      gp2 += cred[ww][m][32 + jl];                                                       \
      op += cred[ww][m][48 + jl];                                                        \
    }                                                                                    \
    float ig = 1.f / (1.f + __expf(-ip));                                                \
    float fg = 1.f / (1.f + __expf(-fp));                                                \
    float ea = __expf(-2.f * fabsf(gp2));                                                \
    float gg = copysignf((1.f - ea) / (1.f + ea), gp2);                                  \
    float og = 1.f / (1.f + __expf(-op));                                                \
    creg = fg * creg + ig * gg;                                                          \
    float eb = __expf(-2.f * fabsf(creg));                                               \
    float hval = og * copysignf((1.f - eb) / (1.f + eb), creg);                          \
    size_t idx = (size_t)(rbase + m) * 1024 + jc * 16 + jl;                              \
    union { f16 h; unsigned short s; } cv; cv.h = (f16)hval;                             \
    __hip_atomic_store((unsigned short*)((HOUT) + idx), cv.s,                            \
                       __ATOMIC_RELAXED, __HIP_MEMORY_SCOPE_AGENT);                      \
    __syncthreads(); /* drains vmcnt(0) per wave: h store ack'd at LLC */                \
    if (tid == 0) {                                                                      \
      unsigned int fv = (unsigned int)(t + 1) & 255u;                                    \
      asm volatile("global_store_byte %0, %1, off sc0 sc1" ::                            \
                   "v"(myflag), "v"(fv) : "memory");                                     \
    }                                                                                    \
  }

#define GLD_X(dst, addr)                                                                 \
  asm volatile("global_load_dwordx4 %0, %1, off sc0 sc1" : "=&v"(dst) : "v"(addr) : "memory")
#define GLD_C(dst, addr)                                                                 \
  asm volatile("global_load_dwordx4 %0, %1, off" : "=&v"(dst) : "v"(addr) : "memory")
#define WAITV(n)                                                                         \
  { asm volatile("s_waitcnt vmcnt(" #n ")" ::: "memory"); __builtin_amdgcn_sched_barrier(0); }

  if (layer == 0) {
    const int KK = 6;
    f16x8 wreg[6][4];
#pragma unroll
    for (int kk = 0; kk < KK; ++kk)
#pragma unroll
      for (int cf = 0; cf < 4; ++cf)
        wreg[kk][cf] = *(const f16x8*)(W0f + ((size_t)((jc * 8 + w) * KK + kk) * 4 + cf) * 512 + lane * 8);
#pragma unroll
    for (int kk = 0; kk < KK; ++kk)
      asm volatile("" : "+v"(wreg[kk][0]), "+v"(wreg[kk][1]), "+v"(wreg[kk][2]), "+v"(wreg[kk][3]));

    for (int t = 0; t < 512; ++t) {
      const f16* A0x = x16 + (size_t)t * 32768;
      const f16* A1h = h0buf + (size_t)((t + 7) & 7) * 65536;  // h0_{t-1}
      f16* hout = h0buf + (size_t)(t & 7) * 65536;             // h0_t

      f16x8 af[6][2];
#define ISSUE_X(kk)                                                                      \
      {                                                                                  \
        int k_ = w * 64 + (kk) * 32 + q8;                                                \
        const f16* ap_ = A0x + k_;                                                       \
        GLD_C(af[kk][0], ap_ + (size_t)(rbase + l15) * 512);                             \
        GLD_C(af[kk][1], ap_ + (size_t)(rbase + 16 + l15) * 512);                        \
      }
#define ISSUE_H0(kk)                                                                     \
      {                                                                                  \
        int hk_ = w * 128 + ((kk) - 2) * 32 + q8;                                        \
        const f16* ap_ = A1h + hk_;                                                      \
        GLD_X(af[kk][0], ap_ + (size_t)(rbase + l15) * 1024);                            \
        GLD_X(af[kk][1], ap_ + (size_t)(rbase + 16 + l15) * 1024);                       \
      }
#define MF0(kk)                                                                          \
      { _Pragma("unroll") for (int rf = 0; rf < 2; ++rf)                                 \
          _Pragma("unroll") for (int cf = 0; cf < 4; ++cf)                               \
            acc[rf][cf] = MFMA16(af[kk][rf], wreg[kk][cf], acc[rf][cf]); }

      f32x4 acc[2][4];
#pragma unroll
      for (int i = 0; i < 2; ++i)
#pragma unroll
        for (int j = 0; j < 4; ++j) acc[i][j] = f32x4{0.f, 0.f, 0.f, 0.f};

      ISSUE_X(0) ISSUE_X(1)          // pure-x slices: flag-independent
      POLLG(t, t - 7);               // h0_{t-1} ready + WAR(L1 >= t-7)
      ISSUE_H0(2) ISSUE_H0(3) ISSUE_H0(4) ISSUE_H0(5)
      WAITV(8)  MF0(0) MF0(1)        // x loads retired
      WAITV(6)  MF0(2)
      WAITV(4)  MF0(3)
      WAITV(2)  MF0(4)
      WAITV(0)  MF0(5)
#undef ISSUE_X
#undef ISSUE_H0
#undef MF0

      CRED_AND_POINTWISE(hout);
    }
  } else {
    const int KK = 8;
    f16x8 wreg[8][4];
#pragma unroll
    for (int kk = 0; kk < KK; ++kk)
#pragma unroll
      for (int cf = 0; cf < 4; ++cf)
        wreg[kk][cf] = *(const f16x8*)(W1f + ((size_t)((jc * 8 + w) * KK + kk) * 4 + cf) * 512 + lane * 8);
#pragma unroll
    for (int kk = 0; kk < KK; ++kk)
      asm volatile("" : "+v"(wreg[kk][0]), "+v"(wreg[kk][1]), "+v"(wreg[kk][2]), "+v"(wreg[kk][3]));

    const int kbeg = w * 256;
    for (int t = 0; t < 512; ++t) {
      const f16* A0 = h0buf + (size_t)(t & 7) * 65536;        // h0_t
      const f16* A1 = h1ring + (size_t)t * 65536;             // h1_{t-1} (slot t)
      f16* hout = h1ring + (size_t)(t + 1) * 65536;           // h1_t (slot t+1)

      POLLG(t + 1, t);

      f16x8 af[4][2];
#define ISSUE1(kk)                                                                       \
      {                                                                                  \
        int k_ = kbeg + (kk) * 32 + q8;                                                  \
        const f16* ap_ = (k_ < 1024) ? (A0 + k_) : (A1 + (k_ - 1024));                   \
        GLD_X(af[(kk) & 3][0], ap_ + (size_t)(rbase + l15) * 1024);                      \
        GLD_X(af[(kk) & 3][1], ap_ + (size_t)(rbase + 16 + l15) * 1024);                 \
      }
#define MF1(kk)                                                                          \
      { _Pragma("unroll") for (int rf = 0; rf < 2; ++rf)                                 \
          _Pragma("unroll") for (int cf = 0; cf < 4; ++cf)                               \
            acc[rf][cf] = MFMA16(af[(kk) & 3][rf], wreg[kk][cf], acc[rf][cf]); }

      f32x4 acc[2][4];
#pragma unroll
      for (int i = 0; i < 2; ++i)
#pragma unroll
        for (int j = 0; j < 4; ++j) acc[i][j] = f32x4{0.f, 0.f, 0.f, 0.f};

      ISSUE1(0) ISSUE1(1) ISSUE1(2) ISSUE1(3)
      WAITV(6) MF1(0) ISSUE1(4)
      WAITV(6) MF1(1) ISSUE1(5)
      WAITV(6) MF1(2) ISSUE1(6)
      WAITV(6) MF1(3) ISSUE1(7)
      WAITV(6) MF1(4)
      WAITV(4) MF1(5)
      WAITV(2) MF1(6)
      WAITV(0) MF1(7)
#undef ISSUE1
#undef MF1

      CRED_AND_POINTWISE(hout);
    }
  }
#undef POLLG
#undef CRED_AND_POINTWISE
#undef GLD_X
#undef GLD_C
#undef WAITV
}

// ---------------- final FC ----------------
__global__ __launch_bounds__(512, 1)
void k_fc(const f16* __restrict__ h1all, const f16* __restrict__ Wfc16,
          const float* __restrict__ bfc, float* __restrict__ out) {
  const int s = blockIdx.x;
  const f16* A = h1all + (size_t)s * 65536;
  __shared__ float credf[8][64][68];

  const int w = threadIdx.x >> 6;
  const int lane = threadIdx.x & 63;
  const int l15 = lane & 15;
  const int ksub = (lane >> 4) << 3;

  f32x4 acc[4][4];
#pragma unroll
  for (int i = 0; i < 4; ++i)
#pragma unroll
    for (int j = 0; j < 4; ++j) acc[i][j] = f32x4{0.f, 0.f, 0.f, 0.f};

  const int kbeg = w * 128, kend = kbeg + 128;
  f16x8 af0[4], bf0[4], af1[4], bf1[4];

  auto LOADK = [&](int kc, f16x8(&a)[4], f16x8(&b)[4]) {
    const f16* ap = A + kc + ksub;
#pragma unroll
    for (int rf = 0; rf < 4; ++rf)
      a[rf] = *(const f16x8*)(ap + (size_t)(rf * 16 + l15) * 1024);
    const f16* bp = Wfc16 + kc + ksub;
#pragma unroll
    for (int cf = 0; cf < 4; ++cf)
      b[cf] = *(const f16x8*)(bp + (size_t)(cf * 16 + l15) * 1024);
  };

  LOADK(kbeg, af0, bf0);
  for (int kc = kbeg; kc < kend; kc += 64) {
    LOADK(kc + 32, af1, bf1);
#pragma unroll
    for (int rf = 0; rf < 4; ++rf)
#pragma unroll
      for (int cf = 0; cf < 4; ++cf) acc[rf][cf] = MFMA16(af0[rf], bf0[cf], acc[rf][cf]);
    if (kc + 64 < kend) LOADK(kc + 64, af0, bf0);
#pragma unroll
    for (int rf = 0; rf < 4; ++rf)
#pragma unroll
      for (int cf = 0; cf < 4; ++cf) acc[rf][cf] = MFMA16(af1[rf], bf1[cf], acc[rf][cf]);
  }

#pragma unroll
  for (int rf = 0; rf < 4; ++rf)
#pragma unroll
    for (int cf = 0; cf < 4; ++cf)
#pragma unroll
      for (int r = 0; r < 4; ++r)
        credf[w][rf * 16 + (lane >> 4) * 4 + r][cf * 16 + l15] = acc[rf][cf][r];

  __syncthreads();

  int m = threadIdx.x >> 3;
  int cbase = (threadIdx.x & 7) * 8;
#pragma unroll
  for (int u = 0; u < 8; ++u) {
    int col = cbase + u;
    float v = bfc[col];
#pragma unroll
    for (int ww = 0; ww < 8; ++ww) v += credf[ww][m][col];
    out[((size_t)m * 512 + s) * 64 + col] = v;
  }
}

// ---------------- host ----------------
extern "C" void kernel_launch(void* const* d_in, const int* in_sizes, int n_in,
                              void* d_out, int out_size, void* d_ws, size_t ws_size,
                              hipStream_t stream) {
  const float* x    = (const float*)d_in[0];
  const float* Wih0 = (const float*)d_in[1];
  const float* Whh0 = (const float*)d_in[2];
  const float* bih0 = (const float*)d_in[3];
  const float* bhh0 = (const float*)d_in[4];
  const float* Wih1 = (const float*)d_in[5];
  const float* Whh1 = (const float*)d_in[6];
  const float* bih1 = (const float*)d_in[7];
  const float* bhh1 = (const float*)d_in[8];
  const float* Wfc  = (const float*)d_in[9];
  const float* bfc  = (const float*)d_in[10];
  float* out = (float*)d_out;

  char* ws = (char*)d_ws;
  f16*   W0f    = (f16*)(ws + 0);           // 12,582,912
  f16*   W1f    = (f16*)(ws + 12582912);    // 16,777,216 -> 29,360,128
  f16*   Wfc16  = (f16*)(ws + 29360128);    // 131,072   -> 29,491,200
  float* b0r    = (float*)(ws + 29491200);  // 16,384    -> 29,507,584
  float* b1r    = (float*)(ws + 29507584);  // 16,384    -> 29,523,968
  f16*   x16    = (f16*)(ws + 29523968);    // 33,554,432 -> 63,078,400
  f16*   h1ring = (f16*)(ws + 63078400);    // 513 * 131,072 = 67,239,936 -> 130,318,336
  f16*   h0buf  = (f16*)(ws + 130318336);   // 8 * 131,072 = 1,048,576 -> 131,366,912
  unsigned char* flags8 = (unsigned char*)(ws + 131366912);  // 256 B

  k_conv_x<<<8192, 256, 0, stream>>>(x, x16);
  k_conv_wfrag<<<12288, 64, 0, stream>>>(Wih0, Whh0, W0f, 512, 6, 0);
  k_conv_wfrag<<<16384, 64, 0, stream>>>(Wih1, Whh1, W1f, 1024, 8, 1);
  k_conv_bias<<<64, 64, 0, stream>>>(bih0, bhh0, b0r);
  k_conv_bias<<<64, 64, 0, stream>>>(bih1, bhh1, b1r);
  k_conv_wfc<<<256, 256, 0, stream>>>(Wfc, Wfc16);
  // zero h1_{-1} slot, h0 ring, flags every launch (graph-replay determinism)
  hipMemsetAsync(ws + 63078400, 0, 131072, stream);            // h1 slot 0
  hipMemsetAsync(ws + 130318336, 0, 1048576 + 256, stream);    // h0 ring + flags

  {
    const f16* x16c = x16; const f16* W0fc = W0f; const float* b0rc = b0r;
    const f16* W1fc = W1f; const float* b1rc = b1r;
    f16 *p0 = h0buf, *p1 = h1ring;
    unsigned char* fl = flags8;
    void* kargs[] = { &x16c, &W0fc, &b0rc, &W1fc, &b1rc, &p0, &p1, &fl };
    hipLaunchCooperativeKernel((void*)k_persist, dim3(256), dim3(512), kargs, 0, stream);
  }

  // h1all = h1 ring slots 1..512
  k_fc<<<512, 512, 0, stream>>>(h1ring + 65536, Wfc16, bfc, out);
}